// Round 2
// baseline (478.767 us; speedup 1.0000x reference)
//
#include <hip/hip_runtime.h>
#include <math.h>

#define B      64
#define T      2048
#define RNN_H  1024
#define EMB    512
#define ATT    128
#define NF     32
#define KW     31
#define PADW   15

#define TT  64               // t-tile per energy block
#define CW  (TT + KW - 1)    // 94 staged cum columns

// ---------------- K1: after_query[b][a] = dot(hidden[b,:], Wdec[a,:]) --------
__global__ __launch_bounds__(256) void k_query(const float* __restrict__ hidden,
                                               const float* __restrict__ Wdec,
                                               float* __restrict__ aq) {
    int gw   = (blockIdx.x * blockDim.x + threadIdx.x) >> 6;  // global wave id = b*ATT + a
    int lane = threadIdx.x & 63;
    int b = gw >> 7, a = gw & (ATT - 1);
    const float4* h = (const float4*)(hidden + b * RNN_H);
    const float4* w = (const float4*)(Wdec   + a * RNN_H);
    float acc = 0.f;
#pragma unroll
    for (int i = 0; i < RNN_H / 4 / 64; ++i) {         // 4 iters
        float4 hv = h[lane + i * 64];
        float4 wv = w[lane + i * 64];
        acc += hv.x * wv.x + hv.y * wv.y + hv.z * wv.z + hv.w * wv.w;
    }
#pragma unroll
    for (int off = 32; off; off >>= 1) acc += __shfl_down(acc, off);
    if (lane == 0) aq[gw] = acc;
}

// ---------------- K2: fused conv1d -> loc-linear -> tanh -> energy ----------
__global__ __launch_bounds__(256) void k_energy(
    const float* __restrict__ cum,       // [B][2][T]
    const float* __restrict__ mem_after, // [B][T][ATT]
    const int*   __restrict__ mask,      // [B][T]
    const float* __restrict__ Wconv,     // [NF][2][KW]
    const float* __restrict__ Wloc,      // [ATT][NF]
    const float* __restrict__ Wenergy,   // [ATT]
    const float* __restrict__ aq,        // [B][ATT]
    float* __restrict__ energies)        // [B][T]
{
    __shared__ float cum_s[2][CW];
    __shared__ float wconv_s[NF * 2 * KW];  // [c][ch][k]
    __shared__ float wloc_s[NF * ATT];      // transposed: [c][a]
    __shared__ float wen_s[ATT];
    __shared__ float aq_s[ATT];
    __shared__ float loc_s[NF * TT];        // [c][t]

    int tid = threadIdx.x;
    int b   = blockIdx.x >> 5;   // T/TT == 32 tiles per batch row
    int tc  = blockIdx.x & 31;
    int t0  = tc * TT;

    for (int i = tid; i < NF * 2 * KW; i += 256) wconv_s[i] = Wconv[i];
    for (int i = tid; i < NF * ATT; i += 256) {
        int c = i >> 7, a = i & (ATT - 1);
        wloc_s[i] = Wloc[a * NF + c];
    }
    if (tid < ATT) { wen_s[tid] = Wenergy[tid]; aq_s[tid] = aq[b * ATT + tid]; }
    for (int i = tid; i < 2 * CW; i += 256) {
        int ch = i / CW, j = i - ch * CW;
        int t  = t0 + j - PADW;
        cum_s[ch][j] = (t >= 0 && t < T) ? cum[(b * 2 + ch) * T + t] : 0.f;
    }
    __syncthreads();

    // conv: loc[c][tl] = sum_{ch,k} cum_s[ch][tl+k] * Wconv[c][ch][k]
    for (int i = tid; i < NF * TT; i += 256) {
        int c = i >> 6, tl = i & 63;
        const float* wc = &wconv_s[c * 2 * KW];
        float acc = 0.f;
#pragma unroll
        for (int k = 0; k < KW; ++k) {
            acc += cum_s[0][tl + k] * wc[k];
            acc += cum_s[1][tl + k] * wc[KW + k];
        }
        loc_s[i] = acc;
    }
    __syncthreads();

    int wv = tid >> 6, lane = tid & 63;
    const float2* wloc2 = (const float2*)wloc_s;
    float2 aq2 = ((const float2*)aq_s)[lane];
    float2 we2 = ((const float2*)wen_s)[lane];

    for (int tl = wv * 16; tl < wv * 16 + 16; ++tl) {
        int t = t0 + tl;
        float2 ma = ((const float2*)(mem_after + (size_t)(b * T + t) * ATT))[lane];
        float ax = 0.f, ay = 0.f;
#pragma unroll
        for (int c = 0; c < NF; ++c) {
            float  l  = loc_s[c * TT + tl];           // LDS broadcast
            float2 wl = wloc2[c * (ATT / 2) + lane];  // contiguous, conflict-free
            ax += l * wl.x; ay += l * wl.y;
        }
        float e0 = tanhf(aq2.x + ax + ma.x);
        float e1 = tanhf(aq2.y + ay + ma.y);
        float s  = we2.x * e0 + we2.y * e1;
#pragma unroll
        for (int off = 32; off; off >>= 1) s += __shfl_down(s, off);
        if (lane == 0)
            energies[b * T + t] = mask[b * T + t] ? -INFINITY : s;
    }
}

// ---------------- K3: softmax over T (in place) + zero context --------------
__global__ __launch_bounds__(256) void k_softmax(float* __restrict__ w,
                                                 float* __restrict__ ctx) {
    int b = blockIdx.x, tid = threadIdx.x;
    ((float2*)(ctx + b * EMB))[tid] = make_float2(0.f, 0.f);  // 256*2 = 512

    float* row = w + b * T;
    float e[8];
    float m = -INFINITY;
#pragma unroll
    for (int j = 0; j < 8; ++j) { e[j] = row[tid + j * 256]; m = fmaxf(m, e[j]); }

    __shared__ float redm[4], reds[4];
#pragma unroll
    for (int off = 32; off; off >>= 1) m = fmaxf(m, __shfl_xor(m, off));
    if ((tid & 63) == 0) redm[tid >> 6] = m;
    __syncthreads();
    m = fmaxf(fmaxf(redm[0], redm[1]), fmaxf(redm[2], redm[3]));

    float s = 0.f;
#pragma unroll
    for (int j = 0; j < 8; ++j) { e[j] = expf(e[j] - m); s += e[j]; }
#pragma unroll
    for (int off = 32; off; off >>= 1) s += __shfl_xor(s, off);
    if ((tid & 63) == 0) reds[tid >> 6] = s;
    __syncthreads();
    s = reds[0] + reds[1] + reds[2] + reds[3];

    float inv = 1.f / s;
#pragma unroll
    for (int j = 0; j < 8; ++j) row[tid + j * 256] = e[j] * inv;
}

// ---------------- K4: context[b][:] += sum_t w[b][t] * memory[b][t][:] ------
__global__ __launch_bounds__(128) void k_context(const float* __restrict__ memory,
                                                 const float* __restrict__ w,
                                                 float* __restrict__ ctx) {
    __shared__ float ws[64];
    int b = blockIdx.x >> 5, tc = blockIdx.x & 31;
    int t0 = tc * 64, tid = threadIdx.x;
    if (tid < 64) ws[tid] = w[b * T + t0 + tid];
    __syncthreads();

    const float4* mem4 = (const float4*)memory + (size_t)(b * T + t0) * (EMB / 4);
    float4 acc = make_float4(0.f, 0.f, 0.f, 0.f);
#pragma unroll 8
    for (int t = 0; t < 64; ++t) {
        float  wt = ws[t];
        float4 m  = mem4[(size_t)t * (EMB / 4) + tid];
        acc.x += wt * m.x; acc.y += wt * m.y; acc.z += wt * m.z; acc.w += wt * m.w;
    }
    float* dst = ctx + b * EMB + tid * 4;
    atomicAdd(dst + 0, acc.x);
    atomicAdd(dst + 1, acc.y);
    atomicAdd(dst + 2, acc.z);
    atomicAdd(dst + 3, acc.w);
}

extern "C" void kernel_launch(void* const* d_in, const int* in_sizes, int n_in,
                              void* d_out, int out_size, void* d_ws, size_t ws_size,
                              hipStream_t stream) {
    const float* hidden    = (const float*)d_in[0];  // [B, RNN_H]
    const float* memory    = (const float*)d_in[1];  // [B, T, EMB]
    const float* mem_after = (const float*)d_in[2];  // [B, T, ATT]
    const float* cum       = (const float*)d_in[3];  // [B, 2, T]
    const int*   mask      = (const int*)  d_in[4];  // [B, T]
    const float* Wdec      = (const float*)d_in[5];  // [ATT, RNN_H]
    const float* Wconv     = (const float*)d_in[6];  // [NF, 2, KW]
    const float* Wloc      = (const float*)d_in[7];  // [ATT, NF]
    const float* Wenergy   = (const float*)d_in[8];  // [1, ATT]

    float* ctx = (float*)d_out;            // [B, EMB]
    float* wts = (float*)d_out + B * EMB;  // [B, T]  (energies, then softmaxed in place)
    float* aq  = (float*)d_ws;             // [B, ATT] scratch (32 KB)

    // K1: one wave per (b,a) output; 8192 waves / 4 waves-per-block = 2048 blocks
    k_query<<<(B * ATT) / 4, 256, 0, stream>>>(hidden, Wdec, aq);

    // K2: grid = B * (T/TT) = 64*32 = 2048 blocks
    k_energy<<<B * (T / TT), 256, 0, stream>>>(cum, mem_after, mask, Wconv, Wloc,
                                               Wenergy, aq, wts);

    // K3: one block per batch row
    k_softmax<<<B, 256, 0, stream>>>(wts, ctx);

    // K4: grid = B * (T/64) = 2048 blocks
    k_context<<<B * (T / 64), 128, 0, stream>>>(memory, wts, ctx);
}

// Round 3
// 476.389 us; speedup vs baseline: 1.0050x; 1.0050x over previous
//
#include <hip/hip_runtime.h>
#include <math.h>

#define B      64
#define T      2048
#define RNN_H  1024
#define EMB    512
#define ATT    128
#define NF     32
#define KW     31
#define PADW   15

#define TT  64               // t-tile per energy block
#define CW  (TT + KW - 1)    // 94 staged cum columns

__device__ __forceinline__ float fast_tanh(float x) {
    x = fminf(fmaxf(x, -15.f), 15.f);
    float e = __expf(2.f * x);
    return (e - 1.f) / (e + 1.f);
}

// ---------------- K1: after_query[b][a] = dot(hidden[b,:], Wdec[a,:]) --------
__global__ __launch_bounds__(256) void k_query(const float* __restrict__ hidden,
                                               const float* __restrict__ Wdec,
                                               float* __restrict__ aq) {
    int gw   = (blockIdx.x * blockDim.x + threadIdx.x) >> 6;  // wave id = b*ATT + a
    int lane = threadIdx.x & 63;
    int b = gw >> 7, a = gw & (ATT - 1);
    const float4* h = (const float4*)(hidden + b * RNN_H);
    const float4* w = (const float4*)(Wdec   + a * RNN_H);
    float acc = 0.f;
#pragma unroll
    for (int i = 0; i < RNN_H / 4 / 64; ++i) {         // 4 iters
        float4 hv = h[lane + i * 64];
        float4 wv = w[lane + i * 64];
        acc += hv.x * wv.x + hv.y * wv.y + hv.z * wv.z + hv.w * wv.w;
    }
#pragma unroll
    for (int off = 32; off; off >>= 1) acc += __shfl_down(acc, off);
    if (lane == 0) aq[gw] = acc;
}

// ---------------- K2: fused conv1d -> loc-linear -> tanh -> energy ----------
// Also zeroes its 16-float slice of ctx (stream-ordered before K3).
__global__ __launch_bounds__(256) void k_energy(
    const float* __restrict__ cum,       // [B][2][T]
    const float* __restrict__ mem_after, // [B][T][ATT]
    const int*   __restrict__ mask,      // [B][T]
    const float* __restrict__ Wconv,     // [NF][2][KW]
    const float* __restrict__ Wloc,      // [ATT][NF]
    const float* __restrict__ Wenergy,   // [ATT]
    const float* __restrict__ aq,        // [B][ATT]
    float* __restrict__ en,              // [B][T] energies (ws scratch)
    float* __restrict__ ctx)             // [B][EMB] (zero-init here)
{
    __shared__ float cum_s[2][CW];
    __shared__ float wconv_s[NF * 2 * KW];  // [c][ch][k]
    __shared__ float wloc_s[NF * ATT];      // transposed: [c][a]
    __shared__ float wen_s[ATT];
    __shared__ float aq_s[ATT];
    __shared__ float loc_s[NF * TT];        // [c][t]

    int tid = threadIdx.x;
    int b   = blockIdx.x >> 5;   // T/TT == 32 tiles per batch row
    int tc  = blockIdx.x & 31;
    int t0  = tc * TT;

    if (tid < 16) ctx[b * EMB + tc * 16 + tid] = 0.f;   // 32 tiles x 16 = EMB

    for (int i = tid; i < NF * 2 * KW; i += 256) wconv_s[i] = Wconv[i];
    for (int i = tid; i < NF * ATT; i += 256) {
        int c = i >> 7, a = i & (ATT - 1);
        wloc_s[i] = Wloc[a * NF + c];
    }
    if (tid < ATT) { wen_s[tid] = Wenergy[tid]; aq_s[tid] = aq[b * ATT + tid]; }
    for (int i = tid; i < 2 * CW; i += 256) {
        int ch = i / CW, j = i - ch * CW;
        int t  = t0 + j - PADW;
        cum_s[ch][j] = (t >= 0 && t < T) ? cum[(b * 2 + ch) * T + t] : 0.f;
    }
    __syncthreads();

    // conv: loc[c][tl] = sum_{ch,k} cum_s[ch][tl+k] * Wconv[c][ch][k]
    for (int i = tid; i < NF * TT; i += 256) {
        int c = i >> 6, tl = i & 63;
        const float* wc = &wconv_s[c * 2 * KW];
        float acc = 0.f;
#pragma unroll
        for (int k = 0; k < KW; ++k) {
            acc += cum_s[0][tl + k] * wc[k];
            acc += cum_s[1][tl + k] * wc[KW + k];
        }
        loc_s[i] = acc;
    }
    __syncthreads();

    int wv = tid >> 6, lane = tid & 63;
    const float2* wloc2 = (const float2*)wloc_s;
    float2 aq2 = ((const float2*)aq_s)[lane];
    float2 we2 = ((const float2*)wen_s)[lane];

    for (int tl = wv * 16; tl < wv * 16 + 16; ++tl) {
        int t = t0 + tl;
        float2 ma = ((const float2*)(mem_after + (size_t)(b * T + t) * ATT))[lane];
        float ax = 0.f, ay = 0.f;
#pragma unroll
        for (int c = 0; c < NF; ++c) {
            float  l  = loc_s[c * TT + tl];           // LDS broadcast (uniform addr)
            float2 wl = wloc2[c * (ATT / 2) + lane];  // contiguous, 2-way = free
            ax += l * wl.x; ay += l * wl.y;
        }
        float e0 = fast_tanh(aq2.x + ax + ma.x);
        float e1 = fast_tanh(aq2.y + ay + ma.y);
        float s  = we2.x * e0 + we2.y * e1;
#pragma unroll
        for (int off = 32; off; off >>= 1) s += __shfl_down(s, off);
        if (lane == 0)
            en[b * T + t] = mask[b * T + t] ? -INFINITY : s;
    }
}

// ---------------- K3: fused softmax + weights write + context ---------------
// Each block: full-row max/sum (redundant but deterministic across the 32
// blocks of a row, L2-resident read), then weights for its 64-t window,
// then the weighted memory sum with one atomicAdd per element.
__global__ __launch_bounds__(128) void k_softmax_ctx(
    const float* __restrict__ en,      // [B][T] energies (ws)
    const float* __restrict__ memory,  // [B][T][EMB]
    float* __restrict__ wts,           // [B][T] softmax weights (output)
    float* __restrict__ ctx)           // [B][EMB] (pre-zeroed, atomic)
{
    __shared__ float redm[2], reds[2];
    __shared__ float ws_[64];
    int b = blockIdx.x >> 5, tc = blockIdx.x & 31;
    int t0 = tc * 64, tid = threadIdx.x;

    const float* row = en + b * T;
    float e[16];
    float m = -INFINITY;
#pragma unroll
    for (int j = 0; j < 16; ++j) { e[j] = row[tid + j * 128]; m = fmaxf(m, e[j]); }
#pragma unroll
    for (int off = 32; off; off >>= 1) m = fmaxf(m, __shfl_xor(m, off));
    if ((tid & 63) == 0) redm[tid >> 6] = m;
    __syncthreads();
    m = fmaxf(redm[0], redm[1]);

    float s = 0.f;
#pragma unroll
    for (int j = 0; j < 16; ++j) s += __expf(e[j] - m);
#pragma unroll
    for (int off = 32; off; off >>= 1) s += __shfl_xor(s, off);
    if ((tid & 63) == 0) reds[tid >> 6] = s;
    __syncthreads();
    float inv = 1.f / (reds[0] + reds[1]);

    // weights for this block's window (reload from L2 — avoids runtime-indexed
    // register array -> scratch, rule #20)
    if (tid < 64) {
        float w = __expf(row[t0 + tid] - m) * inv;
        wts[b * T + t0 + tid] = w;
        ws_[tid] = w;
    }
    __syncthreads();

    const float4* mem4 = (const float4*)memory + (size_t)(b * T + t0) * (EMB / 4);
    float4 acc = make_float4(0.f, 0.f, 0.f, 0.f);
#pragma unroll 8
    for (int t = 0; t < 64; ++t) {
        float  wt = ws_[t];
        float4 mv = mem4[(size_t)t * (EMB / 4) + tid];
        acc.x += wt * mv.x; acc.y += wt * mv.y; acc.z += wt * mv.z; acc.w += wt * mv.w;
    }
    float* dst = ctx + b * EMB + tid * 4;
    atomicAdd(dst + 0, acc.x);
    atomicAdd(dst + 1, acc.y);
    atomicAdd(dst + 2, acc.z);
    atomicAdd(dst + 3, acc.w);
}

extern "C" void kernel_launch(void* const* d_in, const int* in_sizes, int n_in,
                              void* d_out, int out_size, void* d_ws, size_t ws_size,
                              hipStream_t stream) {
    const float* hidden    = (const float*)d_in[0];  // [B, RNN_H]
    const float* memory    = (const float*)d_in[1];  // [B, T, EMB]
    const float* mem_after = (const float*)d_in[2];  // [B, T, ATT]
    const float* cum       = (const float*)d_in[3];  // [B, 2, T]
    const int*   mask      = (const int*)  d_in[4];  // [B, T]
    const float* Wdec      = (const float*)d_in[5];  // [ATT, RNN_H]
    const float* Wconv     = (const float*)d_in[6];  // [NF, 2, KW]
    const float* Wloc      = (const float*)d_in[7];  // [ATT, NF]
    const float* Wenergy   = (const float*)d_in[8];  // [1, ATT]

    float* ctx = (float*)d_out;            // [B, EMB]
    float* wts = (float*)d_out + B * EMB;  // [B, T]
    float* aq  = (float*)d_ws;             // [B, ATT]
    float* en  = (float*)d_ws + B * ATT;   // [B, T] energies scratch

    // K1: one wave per (b,a) output
    k_query<<<(B * ATT) / 4, 256, 0, stream>>>(hidden, Wdec, aq);

    // K2: grid = B * (T/TT) = 2048 blocks; also zeroes ctx
    k_energy<<<B * (T / TT), 256, 0, stream>>>(cum, mem_after, mask, Wconv, Wloc,
                                               Wenergy, aq, en, ctx);

    // K3: fused softmax + context, grid = B * (T/64) = 2048 blocks
    k_softmax_ctx<<<B * (T / 64), 128, 0, stream>>>(en, memory, wts, ctx);
}